// Round 13
// baseline (188.908 us; speedup 1.0000x reference)
//
#include <hip/hip_runtime.h>

// CrossHeadProjectionV2: B=1, N=16, T=S=2048, G=1, I=2, M=16.
// out[n,t,s] = sum_m x[m,t,s]*wq[t][m][n]
//            + sum_i kw2[s,i,n] * (sum_m x[m,t,s]*kw1[s,i,m])
//            + x[n,t,s]*kdd[s,n]
//
// R13: WAVE-SPECIALIZED COALESCING. Wave w owns head-rows {2w,2w+1} for all
// 64 s-quads -> every global load/store instruction is 1 KB contiguous
// (vs 128 B fragments in R11/R12's j-split). hk rank-2 partials now reduce
// across waves via a 16 KB LDS buffer inside the existing barrier structure.
// Carries over: NT input loads (R12 win), kt-in-regs+pin (R8 win), dbuf
// x_lds, nodrain barriers, SBLK=256/TT=8/2048 blocks.

#define TDIM 2048
#define SDIM 2048
#define TT 8
#define SBLK 256
#define THREADS 512

typedef float vf4 __attribute__((ext_vector_type(4)));
typedef float vf2 __attribute__((ext_vector_type(2)));

__device__ __forceinline__ void barrier_nodrain() {
  asm volatile("s_waitcnt lgkmcnt(0)" ::: "memory");
  __builtin_amdgcn_s_barrier();
  asm volatile("" ::: "memory");
}

// Opaque pin: keeps loaded weights register-resident (R8: ~7% win).
__device__ __forceinline__ void pin4(vf4& v) {
  float a = v.x, b = v.y, c = v.z, d = v.w;
  asm volatile("" : "+v"(a), "+v"(b), "+v"(c), "+v"(d));
  v.x = a; v.y = b; v.z = c; v.w = d;
}

// ---- prep: transpose per-s weights to s-minor for coalesced reads ----
__global__ void chp_prep(const float* __restrict__ kw1, const float* __restrict__ kw2,
                         const float* __restrict__ kdd,
                         float* __restrict__ kt1, float* __restrict__ kt2,
                         float* __restrict__ kddt) {
  int tid = blockIdx.x * blockDim.x + threadIdx.x;  // 0 .. 163839
  if (tid < 65536) {
    int im = tid >> 11, s = tid & 2047;
    kt1[tid] = kw1[s * 32 + im];
  } else if (tid < 131072) {
    int v = tid - 65536;
    int im = v >> 11, s = v & 2047;
    kt2[v] = kw2[s * 32 + im];
  } else if (tid < 163840) {
    int v = tid - 131072;
    int n = v >> 11, s = v & 2047;
    kddt[v] = kdd[s * 16 + n];
  }
}

__device__ __forceinline__ vf4 ld4(const float* p) {
  return *reinterpret_cast<const vf4*>(p);
}
__device__ __forceinline__ vf4 ld4nt(const float* p) {
  return __builtin_nontemporal_load(reinterpret_cast<const vf4*>(p));
}
__device__ __forceinline__ void fma4(vf4& d, const vf4& a, const vf4& b) {
  d.x = fmaf(a.x, b.x, d.x); d.y = fmaf(a.y, b.y, d.y);
  d.z = fmaf(a.z, b.z, d.z); d.w = fmaf(a.w, b.w, d.w);
}
__device__ __forceinline__ void fma4s(vf4& d, const vf4& a, float b) {
  d.x = fmaf(a.x, b, d.x); d.y = fmaf(a.y, b, d.y);
  d.z = fmaf(a.z, b, d.z); d.w = fmaf(a.w, b, d.w);
}
__device__ __forceinline__ void add4(vf4& d, const vf4& a) {
  d.x += a.x; d.y += a.y; d.z += a.z; d.w += a.w;
}

template <bool KT>
__global__ __launch_bounds__(THREADS, 4) void chp_main(
    const float* __restrict__ in, const float* __restrict__ w,
    const float* __restrict__ qw1, const float* __restrict__ qw2,
    const float* __restrict__ qdd, const float* __restrict__ kw1,
    const float* __restrict__ kw2, const float* __restrict__ kdd,
    const float* __restrict__ kt1, const float* __restrict__ kt2,
    const float* __restrict__ kddt, float* __restrict__ out) {
  __shared__ vf4 x_lds[2][16][65];     // [buf][m][quad] (pad 65)
  __shared__ float wq_lds[2][256];     // [buf][m*16+n]
  __shared__ vf4 hk_lds[8][2][64];     // [wave][i][quad] partials

  const int tid = threadIdx.x;
  const int wv = tid >> 6;       // wave: owns rows {2wv, 2wv+1}
  const int lane = tid & 63;     // s-quad 0..63
  const int s0 = blockIdx.x * SBLK + lane * 4;
  const int t0 = blockIdx.y * TT;
  const int r0 = 2 * wv;

  // ---- per-thread register weights (own 2 rows, own s-quad), loaded ONCE ----
  vf4 kt1v[2][2], kt2v[2][2], kdv[2];
  if constexpr (KT) {
#pragma unroll
    for (int i = 0; i < 2; ++i)
#pragma unroll
      for (int k = 0; k < 2; ++k) {
        kt1v[i][k] = ld4(kt1 + (size_t)(i * 16 + r0 + k) * SDIM + s0);
        kt2v[i][k] = ld4(kt2 + (size_t)(i * 16 + r0 + k) * SDIM + s0);
      }
#pragma unroll
    for (int k = 0; k < 2; ++k) kdv[k] = ld4(kddt + (size_t)(r0 + k) * SDIM + s0);
  } else {
#pragma unroll
    for (int i = 0; i < 2; ++i)
#pragma unroll
      for (int k = 0; k < 2; ++k)
#pragma unroll
        for (int c = 0; c < 4; ++c) {
          kt1v[i][k][c] = kw1[(size_t)(s0 + c) * 32 + i * 16 + r0 + k];
          kt2v[i][k][c] = kw2[(size_t)(s0 + c) * 32 + i * 16 + r0 + k];
        }
#pragma unroll
    for (int k = 0; k < 2; ++k)
#pragma unroll
      for (int c = 0; c < 4; ++c) kdv[k][c] = kdd[(size_t)(s0 + c) * 16 + r0 + k];
  }
#pragma unroll
  for (int i = 0; i < 2; ++i)
#pragma unroll
    for (int k = 0; k < 2; ++k) { pin4(kt1v[i][k]); pin4(kt2v[i][k]); }
#pragma unroll
  for (int k = 0; k < 2; ++k) pin4(kdv[k]);

  // wq-build: waves 0-3 (tid<256) build the 256 entries; wave-uniform branch.
  const bool builder = (tid < 256);
  const int bm = (tid >> 4) & 15, bn = tid & 15;
  const float wbase = builder ? w[bm * 16 + bn] : 0.0f;

  vf4 xp[2];
  float q1a = 0.f, q1b = 0.f, q2a = 0.f, q2b = 0.f, qd = 0.f;

  auto prefetch = [&](int t) {
    // 1 KB contiguous per wave-instruction (64 lanes x 16 B, same row).
#pragma unroll
    for (int k = 0; k < 2; ++k)
      xp[k] = ld4nt(in + ((size_t)(r0 + k) * TDIM + t) * SDIM + s0);
    if (builder) {
      q1a = qw1[t * 32 + bm];
      q1b = qw1[t * 32 + 16 + bm];
      q2a = qw2[t * 32 + bn];
      q2b = qw2[t * 32 + 16 + bn];
      qd = qdd[t * 16 + bn];
    }
  };
  auto stage = [&](int buf) {
#pragma unroll
    for (int k = 0; k < 2; ++k) x_lds[buf][r0 + k][lane] = xp[k];
    if (builder) {
      float v = fmaf(q1a, q2a, fmaf(q1b, q2b, wbase));
      if (bm == bn) v += 1.0f + qd;
      wq_lds[buf][tid] = v;
    }
  };

  // ---- prologue ----
  prefetch(t0);
  stage(0);
  prefetch(t0 + 1);
  barrier_nodrain();

  int cur = 0;
  for (int tt = 0; tt < TT; ++tt) {
    const int t = t0 + tt;
    const int nxt = cur ^ 1;

    // ---- compute t from LDS buf[cur] ----
    vf4 acc[2];
    vf4 pp0 = (vf4){0.f, 0.f, 0.f, 0.f}, pp1 = pp0;
    acc[0] = (vf4){0.f, 0.f, 0.f, 0.f};
    acc[1] = (vf4){0.f, 0.f, 0.f, 0.f};

#pragma unroll
    for (int m = 0; m < 16; ++m) {
      const vf4 xm = x_lds[cur][m][lane];
      const vf2 wp = *reinterpret_cast<const vf2*>(&wq_lds[cur][m * 16 + r0]);
      fma4s(acc[0], xm, wp.x);
      fma4s(acc[1], xm, wp.y);
      if ((m >> 1) == wv) {  // wave-uniform: own m-rows -> hk partials + k-diag
        const int k = m & 1;
        fma4(pp0, xm, kt1v[0][k]);
        fma4(pp1, xm, kt1v[1][k]);
        fma4(acc[k], xm, kdv[k]);
      }
    }
    // publish this wave's hk partials (covers m = 2wv, 2wv+1)
    hk_lds[wv][0][lane] = pp0;
    hk_lds[wv][1][lane] = pp1;
    barrier_nodrain();  // #1: partials visible (also x_lds[cur] reads done)

    // cross-wave hk reduction: sum the 8 waves' partials for this quad
    vf4 hk0 = (vf4){0.f, 0.f, 0.f, 0.f}, hk1 = hk0;
#pragma unroll
    for (int wsrc = 0; wsrc < 8; ++wsrc) {
      add4(hk0, hk_lds[wsrc][0][lane]);
      add4(hk1, hk_lds[wsrc][1][lane]);
    }
    // epilogue + stores (1 KB contiguous per wave-instruction)
#pragma unroll
    for (int r = 0; r < 2; ++r) {
      fma4(acc[r], hk0, kt2v[0][r]);
      fma4(acc[r], hk1, kt2v[1][r]);
      *reinterpret_cast<vf4*>(out + ((size_t)(r0 + r) * TDIM + t) * SDIM + s0) =
          acc[r];
    }

    // ---- stage t+1 into buf[nxt], then prefetch t+2 ----
    if (tt + 1 < TT) {
      stage(nxt);
      if (tt + 2 < TT) prefetch(t + 2);
    }
    barrier_nodrain();  // #2: stage visible; global prefetch stays in flight
    cur = nxt;
  }
}

extern "C" void kernel_launch(void* const* d_in, const int* in_sizes, int n_in,
                              void* d_out, int out_size, void* d_ws, size_t ws_size,
                              hipStream_t stream) {
  const float* in = (const float*)d_in[0];
  const float* qw1 = (const float*)d_in[1];
  const float* qw2 = (const float*)d_in[2];
  const float* kw1 = (const float*)d_in[3];
  const float* kw2 = (const float*)d_in[4];
  const float* qdd = (const float*)d_in[5];
  const float* kdd = (const float*)d_in[6];
  const float* w = (const float*)d_in[7];
  float* out = (float*)d_out;
  float* ws = (float*)d_ws;

  const bool useKT = (ws_size >= 163840ull * sizeof(float));
  float* kt1 = ws;
  float* kt2 = ws + 65536;
  float* kddt = ws + 131072;

  dim3 grid(SDIM / SBLK, TDIM / TT);  // (8, 256) = 2048 blocks
  if (useKT) {
    hipLaunchKernelGGL(chp_prep, dim3(640), dim3(256), 0, stream, kw1, kw2, kdd, kt1,
                       kt2, kddt);
    hipLaunchKernelGGL((chp_main<true>), grid, dim3(THREADS), 0, stream, in, w, qw1,
                       qw2, qdd, kw1, kw2, kdd, kt1, kt2, kddt, out);
  } else {
    hipLaunchKernelGGL((chp_main<false>), grid, dim3(THREADS), 0, stream, in, w, qw1,
                       qw2, qdd, kw1, kw2, kdd, nullptr, nullptr, nullptr, out);
  }
}

// Round 14
// 145.936 us; speedup vs baseline: 1.2945x; 1.2945x over previous
//
#include <hip/hip_runtime.h>

// CrossHeadProjectionV2: B=1, N=16, T=S=2048, G=1, I=2, M=16.
// out[n,t,s] = sum_m x[m,t,s]*wq[t][m][n]
//            + sum_i kw2[s,i,n] * (sum_m x[m,t,s]*kw1[s,i,m])
//            + x[n,t,s]*kdd[s,n]
//
// R14 = R12 (best: NT input, kt pinned in regs, 512thr j-split, 1 barrier/it)
// with ONE change: register prefetch deepened from 1 tile to 2 tiles
// (prefetch t+3 at iter t; two-slot ping-pong, statically indexed via full
// unroll). Doubles per-wave in-flight HBM bytes at unchanged occupancy
// (4 waves/SIMD is reg-bracket-capped either way).

#define TDIM 2048
#define SDIM 2048
#define TT 8
#define SBLK 256
#define THREADS 512

typedef float vf4 __attribute__((ext_vector_type(4)));

__device__ __forceinline__ void barrier_nodrain() {
  asm volatile("s_waitcnt lgkmcnt(0)" ::: "memory");
  __builtin_amdgcn_s_barrier();
  asm volatile("" ::: "memory");
}

// Opaque pin: keeps loaded weights register-resident (R8: ~7% win).
__device__ __forceinline__ void pin4(vf4& v) {
  float a = v.x, b = v.y, c = v.z, d = v.w;
  asm volatile("" : "+v"(a), "+v"(b), "+v"(c), "+v"(d));
  v.x = a; v.y = b; v.z = c; v.w = d;
}

// ---- prep: transpose per-s weights to s-minor for coalesced reads ----
__global__ void chp_prep(const float* __restrict__ kw1, const float* __restrict__ kw2,
                         const float* __restrict__ kdd,
                         float* __restrict__ kt1, float* __restrict__ kt2,
                         float* __restrict__ kddt) {
  int tid = blockIdx.x * blockDim.x + threadIdx.x;  // 0 .. 163839
  if (tid < 65536) {
    int im = tid >> 11, s = tid & 2047;
    kt1[tid] = kw1[s * 32 + im];
  } else if (tid < 131072) {
    int v = tid - 65536;
    int im = v >> 11, s = v & 2047;
    kt2[v] = kw2[s * 32 + im];
  } else if (tid < 163840) {
    int v = tid - 131072;
    int n = v >> 11, s = v & 2047;
    kddt[v] = kdd[s * 16 + n];
  }
}

__device__ __forceinline__ vf4 ld4(const float* p) {
  return *reinterpret_cast<const vf4*>(p);
}
__device__ __forceinline__ vf4 ld4nt(const float* p) {
  return __builtin_nontemporal_load(reinterpret_cast<const vf4*>(p));
}
__device__ __forceinline__ void fma4(vf4& d, const vf4& a, const vf4& b) {
  d.x = fmaf(a.x, b.x, d.x); d.y = fmaf(a.y, b.y, d.y);
  d.z = fmaf(a.z, b.z, d.z); d.w = fmaf(a.w, b.w, d.w);
}
__device__ __forceinline__ void fma4s(vf4& d, const vf4& a, float b) {
  d.x = fmaf(a.x, b, d.x); d.y = fmaf(a.y, b, d.y);
  d.z = fmaf(a.z, b, d.z); d.w = fmaf(a.w, b, d.w);
}

template <bool KT>
__global__ __launch_bounds__(THREADS, 4) void chp_main(
    const float* __restrict__ in, const float* __restrict__ w,
    const float* __restrict__ qw1, const float* __restrict__ qw2,
    const float* __restrict__ qdd, const float* __restrict__ kw1,
    const float* __restrict__ kw2, const float* __restrict__ kdd,
    const float* __restrict__ kt1, const float* __restrict__ kt2,
    const float* __restrict__ kddt, float* __restrict__ out) {
  // x_lds[buf][m][quad], rows padded to 65 quads.
  __shared__ vf4 x_lds[2][16][65];
  __shared__ float wq_lds[2][256];

  const int tid = threadIdx.x;
  const int wv = tid >> 6;
  const int lane = tid & 63;
  const int j = lane & 7;        // owns rows {2j, 2j+1}
  const int qg = lane >> 3;      // quad within wave: 0..7
  const int quad = wv * 8 + qg;  // quad within block: 0..63
  const int s0 = blockIdx.x * SBLK + quad * 4;
  const int t0 = blockIdx.y * TT;

  // ---- per-thread register weights (own 2 rows, own s-quad), loaded ONCE ----
  vf4 kt1v[2][2], kt2v[2][2], kdv[2];
  if constexpr (KT) {
#pragma unroll
    for (int i = 0; i < 2; ++i)
#pragma unroll
      for (int k = 0; k < 2; ++k) {
        kt1v[i][k] = ld4(kt1 + (size_t)(i * 16 + 2 * j + k) * SDIM + s0);
        kt2v[i][k] = ld4(kt2 + (size_t)(i * 16 + 2 * j + k) * SDIM + s0);
      }
#pragma unroll
    for (int k = 0; k < 2; ++k) kdv[k] = ld4(kddt + (size_t)(2 * j + k) * SDIM + s0);
  } else {
#pragma unroll
    for (int i = 0; i < 2; ++i)
#pragma unroll
      for (int k = 0; k < 2; ++k)
#pragma unroll
        for (int c = 0; c < 4; ++c) {
          kt1v[i][k][c] = kw1[(size_t)(s0 + c) * 32 + i * 16 + 2 * j + k];
          kt2v[i][k][c] = kw2[(size_t)(s0 + c) * 32 + i * 16 + 2 * j + k];
        }
#pragma unroll
    for (int k = 0; k < 2; ++k)
#pragma unroll
      for (int c = 0; c < 4; ++c) kdv[k][c] = kdd[(size_t)(s0 + c) * 16 + 2 * j + k];
  }
#pragma unroll
  for (int i = 0; i < 2; ++i)
#pragma unroll
    for (int k = 0; k < 2; ++k) { pin4(kt1v[i][k]); pin4(kt2v[i][k]); }
#pragma unroll
  for (int k = 0; k < 2; ++k) pin4(kdv[k]);

  // wq-build: waves 0-3 (tid<256) build the 256 entries; wave-uniform branch.
  const bool builder = (tid < 256);
  const int bm = (tid >> 4) & 15, bn = tid & 15;
  const float wbase = builder ? w[bm * 16 + bn] : 0.0f;

  // 2-slot prefetch pipeline (statically indexed after full unroll).
  vf4 xpr[2][2];
  float q1a[2], q1b[2], q2a[2], q2b[2], qd[2];

  auto prefetch = [&](int t, int slot) {
#pragma unroll
    for (int k = 0; k < 2; ++k)
      xpr[slot][k] = ld4nt(in + ((size_t)(2 * j + k) * TDIM + t) * SDIM + s0);
    if (builder) {
      q1a[slot] = qw1[t * 32 + bm];
      q1b[slot] = qw1[t * 32 + 16 + bm];
      q2a[slot] = qw2[t * 32 + bn];
      q2b[slot] = qw2[t * 32 + 16 + bn];
      qd[slot] = qdd[t * 16 + bn];
    }
  };
  auto stage = [&](int buf, int slot) {
#pragma unroll
    for (int k = 0; k < 2; ++k) x_lds[buf][2 * j + k][quad] = xpr[slot][k];
    if (builder) {
      float v = fmaf(q1a[slot], q2a[slot], fmaf(q1b[slot], q2b[slot], wbase));
      if (bm == bn) v += 1.0f + qd[slot];
      wq_lds[buf][tid] = v;
    }
  };

  // ---- prologue: stage t0; fill both prefetch slots (t1, t2) ----
  prefetch(t0, 0);
  stage(0, 0);
  prefetch(t0 + 1, 0);
  prefetch(t0 + 2, 1);
  barrier_nodrain();

  int cur = 0;
#pragma unroll
  for (int tt = 0; tt < TT; ++tt) {
    const int t = t0 + tt;
    const int nxt = cur ^ 1;
    const int slot = tt & 1;

    // ---- compute t from LDS buf[cur] ----
    vf4 acc[2];
    vf4 p0 = (vf4){0.f, 0.f, 0.f, 0.f}, p1 = p0;
    acc[0] = (vf4){0.f, 0.f, 0.f, 0.f};
    acc[1] = (vf4){0.f, 0.f, 0.f, 0.f};

#pragma unroll
    for (int m = 0; m < 16; ++m) {
      const vf4 xm = x_lds[cur][m][quad];
      const float* wp = &wq_lds[cur][m * 16 + 2 * j];
      fma4s(acc[0], xm, wp[0]);
      fma4s(acc[1], xm, wp[1]);
      if ((m >> 1) == j) {  // own rows: hk partials + k-diag
        const int k = m & 1;
        fma4(p0, xm, kt1v[0][k]);
        fma4(p1, xm, kt1v[1][k]);
        fma4(acc[k], xm, kdv[k]);
      }
    }
    // butterfly over the 8 j-lanes (same qg): full hk at every lane
#pragma unroll
    for (int mask = 1; mask <= 4; mask <<= 1) {
      p0.x += __shfl_xor(p0.x, mask); p0.y += __shfl_xor(p0.y, mask);
      p0.z += __shfl_xor(p0.z, mask); p0.w += __shfl_xor(p0.w, mask);
      p1.x += __shfl_xor(p1.x, mask); p1.y += __shfl_xor(p1.y, mask);
      p1.z += __shfl_xor(p1.z, mask); p1.w += __shfl_xor(p1.w, mask);
    }
    // epilogue + stores
#pragma unroll
    for (int r = 0; r < 2; ++r) {
      fma4(acc[r], p0, kt2v[0][r]);
      fma4(acc[r], p1, kt2v[1][r]);
      *reinterpret_cast<vf4*>(out + ((size_t)(2 * j + r) * TDIM + t) * SDIM + s0) =
          acc[r];
    }

    // ---- stage t+1 (loaded 2 iters ago) into buf[nxt]; prefetch t+3 ----
    if (tt + 1 < TT) {
      stage(nxt, slot);
      if (tt + 3 < TT) prefetch(t + 3, slot);
    }
    // DS handoff drained; global prefetch (2 tiles deep) stays in flight.
    barrier_nodrain();
    cur = nxt;
  }
}

extern "C" void kernel_launch(void* const* d_in, const int* in_sizes, int n_in,
                              void* d_out, int out_size, void* d_ws, size_t ws_size,
                              hipStream_t stream) {
  const float* in = (const float*)d_in[0];
  const float* qw1 = (const float*)d_in[1];
  const float* qw2 = (const float*)d_in[2];
  const float* kw1 = (const float*)d_in[3];
  const float* kw2 = (const float*)d_in[4];
  const float* qdd = (const float*)d_in[5];
  const float* kdd = (const float*)d_in[6];
  const float* w = (const float*)d_in[7];
  float* out = (float*)d_out;
  float* ws = (float*)d_ws;

  const bool useKT = (ws_size >= 163840ull * sizeof(float));
  float* kt1 = ws;
  float* kt2 = ws + 65536;
  float* kddt = ws + 131072;

  dim3 grid(SDIM / SBLK, TDIM / TT);  // (8, 256) = 2048 blocks
  if (useKT) {
    hipLaunchKernelGGL(chp_prep, dim3(640), dim3(256), 0, stream, kw1, kw2, kdd, kt1,
                       kt2, kddt);
    hipLaunchKernelGGL((chp_main<true>), grid, dim3(THREADS), 0, stream, in, w, qw1,
                       qw2, qdd, kw1, kw2, kdd, kt1, kt2, kddt, out);
  } else {
    hipLaunchKernelGGL((chp_main<false>), grid, dim3(THREADS), 0, stream, in, w, qw1,
                       qw2, qdd, kw1, kw2, kdd, nullptr, nullptr, nullptr, out);
  }
}

// Round 15
// 143.218 us; speedup vs baseline: 1.3190x; 1.0190x over previous
//
#include <hip/hip_runtime.h>

// CrossHeadProjectionV2: B=1, N=16, T=S=2048, G=1, I=2, M=16.
// out[n,t,s] = sum_m x[m,t,s]*wq[t][m][n]
//            + sum_i kw2[s,i,n] * (sum_m x[m,t,s]*kw1[s,i,m])
//            + x[n,t,s]*kdd[s,n]
//
// R15 = R12 + DS-pipe cuts. DS audit: R12 issues ~42 DS ops/wave-iter
// (16 x-b128 + 16 wq-b64 + writes + swizzles) -> DS issue ~100% busy at
// 12.5 waves/CU, explaining why occupancy/barriers/prefetch all failed.
// Changes: (1) wq stored TRANSPOSED [n][m] padded [16][20] (80B rows,
// 16B-aligned), read as b128 chunks of 4 m -> wq reads 16->8 instrs.
// (2) NT stores (L3 now serves only kt; output lines have no read reuse).

#define TDIM 2048
#define SDIM 2048
#define TT 8
#define SBLK 256
#define THREADS 512

typedef float vf4 __attribute__((ext_vector_type(4)));

__device__ __forceinline__ void barrier_nodrain() {
  asm volatile("s_waitcnt lgkmcnt(0)" ::: "memory");
  __builtin_amdgcn_s_barrier();
  asm volatile("" ::: "memory");
}

// Opaque pin: keeps loaded weights register-resident (R8: ~7% win).
__device__ __forceinline__ void pin4(vf4& v) {
  float a = v.x, b = v.y, c = v.z, d = v.w;
  asm volatile("" : "+v"(a), "+v"(b), "+v"(c), "+v"(d));
  v.x = a; v.y = b; v.z = c; v.w = d;
}

// ---- prep: transpose per-s weights to s-minor for coalesced reads ----
__global__ void chp_prep(const float* __restrict__ kw1, const float* __restrict__ kw2,
                         const float* __restrict__ kdd,
                         float* __restrict__ kt1, float* __restrict__ kt2,
                         float* __restrict__ kddt) {
  int tid = blockIdx.x * blockDim.x + threadIdx.x;  // 0 .. 163839
  if (tid < 65536) {
    int im = tid >> 11, s = tid & 2047;
    kt1[tid] = kw1[s * 32 + im];
  } else if (tid < 131072) {
    int v = tid - 65536;
    int im = v >> 11, s = v & 2047;
    kt2[v] = kw2[s * 32 + im];
  } else if (tid < 163840) {
    int v = tid - 131072;
    int n = v >> 11, s = v & 2047;
    kddt[v] = kdd[s * 16 + n];
  }
}

__device__ __forceinline__ vf4 ld4(const float* p) {
  return *reinterpret_cast<const vf4*>(p);
}
__device__ __forceinline__ vf4 ld4nt(const float* p) {
  return __builtin_nontemporal_load(reinterpret_cast<const vf4*>(p));
}
__device__ __forceinline__ void fma4(vf4& d, const vf4& a, const vf4& b) {
  d.x = fmaf(a.x, b.x, d.x); d.y = fmaf(a.y, b.y, d.y);
  d.z = fmaf(a.z, b.z, d.z); d.w = fmaf(a.w, b.w, d.w);
}
__device__ __forceinline__ void fma4s(vf4& d, const vf4& a, float b) {
  d.x = fmaf(a.x, b, d.x); d.y = fmaf(a.y, b, d.y);
  d.z = fmaf(a.z, b, d.z); d.w = fmaf(a.w, b, d.w);
}

template <bool KT>
__global__ __launch_bounds__(THREADS, 4) void chp_main(
    const float* __restrict__ in, const float* __restrict__ w,
    const float* __restrict__ qw1, const float* __restrict__ qw2,
    const float* __restrict__ qdd, const float* __restrict__ kw1,
    const float* __restrict__ kw2, const float* __restrict__ kdd,
    const float* __restrict__ kt1, const float* __restrict__ kt2,
    const float* __restrict__ kddt, float* __restrict__ out) {
  // x_lds[buf][m][quad], rows padded to 65 quads.
  __shared__ vf4 x_lds[2][16][65];
  // wq TRANSPOSED: [buf][n][m], rows padded to 20 floats (80B, 16B-aligned).
  __shared__ float wqT_lds[2][16][20];

  const int tid = threadIdx.x;
  const int wv = tid >> 6;
  const int lane = tid & 63;
  const int j = lane & 7;        // owns rows {2j, 2j+1}
  const int qg = lane >> 3;      // quad within wave: 0..7
  const int quad = wv * 8 + qg;  // quad within block: 0..63
  const int s0 = blockIdx.x * SBLK + quad * 4;
  const int t0 = blockIdx.y * TT;

  // ---- per-thread register weights (own 2 rows, own s-quad), loaded ONCE ----
  vf4 kt1v[2][2], kt2v[2][2], kdv[2];
  if constexpr (KT) {
#pragma unroll
    for (int i = 0; i < 2; ++i)
#pragma unroll
      for (int k = 0; k < 2; ++k) {
        kt1v[i][k] = ld4(kt1 + (size_t)(i * 16 + 2 * j + k) * SDIM + s0);
        kt2v[i][k] = ld4(kt2 + (size_t)(i * 16 + 2 * j + k) * SDIM + s0);
      }
#pragma unroll
    for (int k = 0; k < 2; ++k) kdv[k] = ld4(kddt + (size_t)(2 * j + k) * SDIM + s0);
  } else {
#pragma unroll
    for (int i = 0; i < 2; ++i)
#pragma unroll
      for (int k = 0; k < 2; ++k)
#pragma unroll
        for (int c = 0; c < 4; ++c) {
          kt1v[i][k][c] = kw1[(size_t)(s0 + c) * 32 + i * 16 + 2 * j + k];
          kt2v[i][k][c] = kw2[(size_t)(s0 + c) * 32 + i * 16 + 2 * j + k];
        }
#pragma unroll
    for (int k = 0; k < 2; ++k)
#pragma unroll
      for (int c = 0; c < 4; ++c) kdv[k][c] = kdd[(size_t)(s0 + c) * 16 + 2 * j + k];
  }
#pragma unroll
  for (int i = 0; i < 2; ++i)
#pragma unroll
    for (int k = 0; k < 2; ++k) { pin4(kt1v[i][k]); pin4(kt2v[i][k]); }
#pragma unroll
  for (int k = 0; k < 2; ++k) pin4(kdv[k]);

  // wq-build: waves 0-3 (tid<256) build the 256 entries; wave-uniform branch.
  const bool builder = (tid < 256);
  const int bm = (tid >> 4) & 15, bn = tid & 15;
  const float wbase = builder ? w[bm * 16 + bn] : 0.0f;

  vf4 xp[2];
  float q1a = 0.f, q1b = 0.f, q2a = 0.f, q2b = 0.f, qd = 0.f;

  auto prefetch = [&](int t) {
#pragma unroll
    for (int k = 0; k < 2; ++k)
      xp[k] = ld4nt(in + ((size_t)(2 * j + k) * TDIM + t) * SDIM + s0);
    if (builder) {
      q1a = qw1[t * 32 + bm];
      q1b = qw1[t * 32 + 16 + bm];
      q2a = qw2[t * 32 + bn];
      q2b = qw2[t * 32 + 16 + bn];
      qd = qdd[t * 16 + bn];
    }
  };
  auto stage = [&](int buf) {
#pragma unroll
    for (int k = 0; k < 2; ++k) x_lds[buf][2 * j + k][quad] = xp[k];
    if (builder) {
      float v = fmaf(q1a, q2a, fmaf(q1b, q2b, wbase));
      if (bm == bn) v += 1.0f + qd;
      wqT_lds[buf][bn][bm] = v;  // transposed store
    }
  };

  // ---- prologue: prefetch + stage t0, prefetch t0+1 ----
  prefetch(t0);
  stage(0);
  prefetch(t0 + 1);
  barrier_nodrain();

  int cur = 0;
  for (int tt = 0; tt < TT; ++tt) {
    const int t = t0 + tt;
    const int nxt = cur ^ 1;

    // ---- compute t from LDS buf[cur] ----
    vf4 acc[2];
    vf4 p0 = (vf4){0.f, 0.f, 0.f, 0.f}, p1 = p0;
    acc[0] = (vf4){0.f, 0.f, 0.f, 0.f};
    acc[1] = (vf4){0.f, 0.f, 0.f, 0.f};

#pragma unroll
    for (int mq = 0; mq < 4; ++mq) {
      // wq rows for own n's, 4 m at a time via b128 (was 16 b64 total).
      const vf4 wr0 =
          *reinterpret_cast<const vf4*>(&wqT_lds[cur][2 * j][mq * 4]);
      const vf4 wr1 =
          *reinterpret_cast<const vf4*>(&wqT_lds[cur][2 * j + 1][mq * 4]);
#pragma unroll
      for (int mm = 0; mm < 4; ++mm) {
        const int m = mq * 4 + mm;
        const vf4 xm = x_lds[cur][m][quad];
        fma4s(acc[0], xm, wr0[mm]);
        fma4s(acc[1], xm, wr1[mm]);
        if ((m >> 1) == j) {  // own rows: hk partials + k-diag
          const int k = m & 1;
          fma4(p0, xm, kt1v[0][k]);
          fma4(p1, xm, kt1v[1][k]);
          fma4(acc[k], xm, kdv[k]);
        }
      }
    }
    // butterfly over the 8 j-lanes (same qg): full hk at every lane
#pragma unroll
    for (int mask = 1; mask <= 4; mask <<= 1) {
      p0.x += __shfl_xor(p0.x, mask); p0.y += __shfl_xor(p0.y, mask);
      p0.z += __shfl_xor(p0.z, mask); p0.w += __shfl_xor(p0.w, mask);
      p1.x += __shfl_xor(p1.x, mask); p1.y += __shfl_xor(p1.y, mask);
      p1.z += __shfl_xor(p1.z, mask); p1.w += __shfl_xor(p1.w, mask);
    }
    // epilogue + NT stores (output has zero read-reuse; keep L3 for kt)
#pragma unroll
    for (int r = 0; r < 2; ++r) {
      fma4(acc[r], p0, kt2v[0][r]);
      fma4(acc[r], p1, kt2v[1][r]);
      __builtin_nontemporal_store(
          acc[r],
          reinterpret_cast<vf4*>(out + ((size_t)(2 * j + r) * TDIM + t) * SDIM + s0));
    }

    // ---- stage t+1 into buf[nxt], then prefetch t+2 ----
    if (tt + 1 < TT) {
      stage(nxt);
      if (tt + 2 < TT) prefetch(t + 2);
    }
    // DS handoff drained; global prefetch stays in flight.
    barrier_nodrain();
    cur = nxt;
  }
}

extern "C" void kernel_launch(void* const* d_in, const int* in_sizes, int n_in,
                              void* d_out, int out_size, void* d_ws, size_t ws_size,
                              hipStream_t stream) {
  const float* in = (const float*)d_in[0];
  const float* qw1 = (const float*)d_in[1];
  const float* qw2 = (const float*)d_in[2];
  const float* kw1 = (const float*)d_in[3];
  const float* kw2 = (const float*)d_in[4];
  const float* qdd = (const float*)d_in[5];
  const float* kdd = (const float*)d_in[6];
  const float* w = (const float*)d_in[7];
  float* out = (float*)d_out;
  float* ws = (float*)d_ws;

  const bool useKT = (ws_size >= 163840ull * sizeof(float));
  float* kt1 = ws;
  float* kt2 = ws + 65536;
  float* kddt = ws + 131072;

  dim3 grid(SDIM / SBLK, TDIM / TT);  // (8, 256) = 2048 blocks
  if (useKT) {
    hipLaunchKernelGGL(chp_prep, dim3(640), dim3(256), 0, stream, kw1, kw2, kdd, kt1,
                       kt2, kddt);
    hipLaunchKernelGGL((chp_main<true>), grid, dim3(THREADS), 0, stream, in, w, qw1,
                       qw2, qdd, kw1, kw2, kdd, kt1, kt2, kddt, out);
  } else {
    hipLaunchKernelGGL((chp_main<false>), grid, dim3(THREADS), 0, stream, in, w, qw1,
                       qw2, qdd, kw1, kw2, kdd, nullptr, nullptr, nullptr, out);
  }
}

// Round 16
// 139.916 us; speedup vs baseline: 1.3502x; 1.0236x over previous
//
#include <hip/hip_runtime.h>

// CrossHeadProjectionV2: B=1, N=16, T=S=2048, G=1, I=2, M=16.
// out[n,t,s] = sum_m x[m,t,s]*wq[t][m][n]
//            + sum_i kw2[s,i,n] * (sum_m x[m,t,s]*kw1[s,i,m])
//            + x[n,t,s]*kdd[s,n]
//
// R16 = R12 (NT input loads, pinned kt regs, 512thr, j-split) made fully
// WAVE-AUTONOMOUS: wave-private padded LDS staging, every wave builds its own
// wq, ZERO barriers. Tests the last untested structural difference from a
// copy kernel: per-iteration barrier convoying (all 8 waves wait on the
// slowest wave's HBM load every iteration + phase-locked load-issue bursts).
// Correctness: per-wave program order + in-order DS pipe (R5 validated).

#define TDIM 2048
#define SDIM 2048
#define TT 8
#define SBLK 256
#define THREADS 512

typedef float vf4 __attribute__((ext_vector_type(4)));

// Opaque pin: keeps loaded weights register-resident (R8: ~7% win).
__device__ __forceinline__ void pin4(vf4& v) {
  float a = v.x, b = v.y, c = v.z, d = v.w;
  asm volatile("" : "+v"(a), "+v"(b), "+v"(c), "+v"(d));
  v.x = a; v.y = b; v.z = c; v.w = d;
}

// ---- prep: transpose per-s weights to s-minor for coalesced reads ----
__global__ void chp_prep(const float* __restrict__ kw1, const float* __restrict__ kw2,
                         const float* __restrict__ kdd,
                         float* __restrict__ kt1, float* __restrict__ kt2,
                         float* __restrict__ kddt) {
  int tid = blockIdx.x * blockDim.x + threadIdx.x;  // 0 .. 163839
  if (tid < 65536) {
    int im = tid >> 11, s = tid & 2047;
    kt1[tid] = kw1[s * 32 + im];
  } else if (tid < 131072) {
    int v = tid - 65536;
    int im = v >> 11, s = v & 2047;
    kt2[v] = kw2[s * 32 + im];
  } else if (tid < 163840) {
    int v = tid - 131072;
    int n = v >> 11, s = v & 2047;
    kddt[v] = kdd[s * 16 + n];
  }
}

__device__ __forceinline__ vf4 ld4(const float* p) {
  return *reinterpret_cast<const vf4*>(p);
}
__device__ __forceinline__ vf4 ld4nt(const float* p) {
  return __builtin_nontemporal_load(reinterpret_cast<const vf4*>(p));
}
__device__ __forceinline__ void fma4(vf4& d, const vf4& a, const vf4& b) {
  d.x = fmaf(a.x, b.x, d.x); d.y = fmaf(a.y, b.y, d.y);
  d.z = fmaf(a.z, b.z, d.z); d.w = fmaf(a.w, b.w, d.w);
}
__device__ __forceinline__ void fma4s(vf4& d, const vf4& a, float b) {
  d.x = fmaf(a.x, b, d.x); d.y = fmaf(a.y, b, d.y);
  d.z = fmaf(a.z, b, d.z); d.w = fmaf(a.w, b, d.w);
}

template <bool KT>
__global__ __launch_bounds__(THREADS, 4) void chp_main(
    const float* __restrict__ in, const float* __restrict__ w,
    const float* __restrict__ qw1, const float* __restrict__ qw2,
    const float* __restrict__ qdd, const float* __restrict__ kw1,
    const float* __restrict__ kw2, const float* __restrict__ kdd,
    const float* __restrict__ kt1, const float* __restrict__ kt2,
    const float* __restrict__ kddt, float* __restrict__ out) {
  // Wave-private staging, single-buffered (per-wave program order + in-order
  // DS pipe => no barrier needed). x rows padded to 9 quads (writes land
  // <=2-way per bank = free per m136; reads are 8-addr broadcast).
  __shared__ vf4 x_lds[8][16][9];
  __shared__ float wq_lds[8][256];

  const int tid = threadIdx.x;
  const int wv = tid >> 6;
  const int lane = tid & 63;
  const int j = lane & 7;    // owns rows {2j, 2j+1}
  const int qg = lane >> 3;  // quad within the wave's 32-s slab: 0..7
  const int s0 = blockIdx.x * SBLK + wv * 32 + qg * 4;
  const int t0 = blockIdx.y * TT;

  // ---- per-thread register weights (own 2 rows, own s-quad), loaded ONCE ----
  vf4 kt1v[2][2], kt2v[2][2], kdv[2];
  if constexpr (KT) {
#pragma unroll
    for (int i = 0; i < 2; ++i)
#pragma unroll
      for (int k = 0; k < 2; ++k) {
        kt1v[i][k] = ld4(kt1 + (size_t)(i * 16 + 2 * j + k) * SDIM + s0);
        kt2v[i][k] = ld4(kt2 + (size_t)(i * 16 + 2 * j + k) * SDIM + s0);
      }
#pragma unroll
    for (int k = 0; k < 2; ++k) kdv[k] = ld4(kddt + (size_t)(2 * j + k) * SDIM + s0);
  } else {
#pragma unroll
    for (int i = 0; i < 2; ++i)
#pragma unroll
      for (int k = 0; k < 2; ++k)
#pragma unroll
        for (int c = 0; c < 4; ++c) {
          kt1v[i][k][c] = kw1[(size_t)(s0 + c) * 32 + i * 16 + 2 * j + k];
          kt2v[i][k][c] = kw2[(size_t)(s0 + c) * 32 + i * 16 + 2 * j + k];
        }
#pragma unroll
    for (int k = 0; k < 2; ++k)
#pragma unroll
      for (int c = 0; c < 4; ++c) kdv[k][c] = kdd[(size_t)(s0 + c) * 16 + 2 * j + k];
  }
#pragma unroll
  for (int i = 0; i < 2; ++i)
#pragma unroll
    for (int k = 0; k < 2; ++k) { pin4(kt1v[i][k]); pin4(kt2v[i][k]); }
#pragma unroll
  for (int k = 0; k < 2; ++k) pin4(kdv[k]);

  // wq-build, wave-local: lane builds entries (bm, bn0..bn0+3).
  const int bm = lane >> 2;
  const int bn0 = (lane & 3) * 4;
  const vf4 wb4 = ld4(w + bm * 16 + bn0);  // t-invariant

  vf4 xp[2];
  float q1a = 0.f, q1b = 0.f;
  vf4 q2a, q2b, qdv4;

  auto prefetch = [&](int t) {
#pragma unroll
    for (int k = 0; k < 2; ++k)
      xp[k] = ld4nt(in + ((size_t)(2 * j + k) * TDIM + t) * SDIM + s0);
    q1a = qw1[t * 32 + bm];
    q1b = qw1[t * 32 + 16 + bm];
    q2a = ld4(qw2 + t * 32 + bn0);
    q2b = ld4(qw2 + t * 32 + 16 + bn0);
    qdv4 = ld4(qdd + t * 16 + bn0);
  };
  auto stage = [&]() {
#pragma unroll
    for (int k = 0; k < 2; ++k) x_lds[wv][2 * j + k][qg] = xp[k];
    vf4 v;
#pragma unroll
    for (int c = 0; c < 4; ++c) {
      v[c] = fmaf(q1a, q2a[c], fmaf(q1b, q2b[c], wb4[c]));
      v[c] += (bm == bn0 + c) ? (1.0f + qdv4[c]) : 0.0f;
    }
    *reinterpret_cast<vf4*>(&wq_lds[wv][bm * 16 + bn0]) = v;
  };

  // ---- prologue: prefetch + stage t0, prefetch t0+1. NO BARRIERS. ----
  prefetch(t0);
  stage();
  prefetch(t0 + 1);

  for (int tt = 0; tt < TT; ++tt) {
    const int t = t0 + tt;

    // ---- compute t from this wave's private LDS ----
    vf4 acc[2];
    vf4 p0 = (vf4){0.f, 0.f, 0.f, 0.f}, p1 = p0;
    acc[0] = (vf4){0.f, 0.f, 0.f, 0.f};
    acc[1] = (vf4){0.f, 0.f, 0.f, 0.f};

#pragma unroll
    for (int m = 0; m < 16; ++m) {
      const vf4 xm = x_lds[wv][m][qg];
      const float* wp = &wq_lds[wv][m * 16 + 2 * j];
      fma4s(acc[0], xm, wp[0]);
      fma4s(acc[1], xm, wp[1]);
      if ((m >> 1) == j) {  // own rows: hk partials + k-diag
        const int k = m & 1;
        fma4(p0, xm, kt1v[0][k]);
        fma4(p1, xm, kt1v[1][k]);
        fma4(acc[k], xm, kdv[k]);
      }
    }
    // butterfly over the 8 j-lanes (lanes qg*8 .. qg*8+7)
#pragma unroll
    for (int mask = 1; mask <= 4; mask <<= 1) {
      p0.x += __shfl_xor(p0.x, mask); p0.y += __shfl_xor(p0.y, mask);
      p0.z += __shfl_xor(p0.z, mask); p0.w += __shfl_xor(p0.w, mask);
      p1.x += __shfl_xor(p1.x, mask); p1.y += __shfl_xor(p1.y, mask);
      p1.z += __shfl_xor(p1.z, mask); p1.w += __shfl_xor(p1.w, mask);
    }
    // epilogue + stores
#pragma unroll
    for (int r = 0; r < 2; ++r) {
      fma4(acc[r], p0, kt2v[0][r]);
      fma4(acc[r], p1, kt2v[1][r]);
      *reinterpret_cast<vf4*>(out + ((size_t)(2 * j + r) * TDIM + t) * SDIM + s0) =
          acc[r];
    }

    // ---- overwrite own staging with t+1 (in-order DS => safe), prefetch t+2.
    if (tt + 1 < TT) {
      stage();
      if (tt + 2 < TT) prefetch(t + 2);
    }
  }
}

extern "C" void kernel_launch(void* const* d_in, const int* in_sizes, int n_in,
                              void* d_out, int out_size, void* d_ws, size_t ws_size,
                              hipStream_t stream) {
  const float* in = (const float*)d_in[0];
  const float* qw1 = (const float*)d_in[1];
  const float* qw2 = (const float*)d_in[2];
  const float* kw1 = (const float*)d_in[3];
  const float* kw2 = (const float*)d_in[4];
  const float* qdd = (const float*)d_in[5];
  const float* kdd = (const float*)d_in[6];
  const float* w = (const float*)d_in[7];
  float* out = (float*)d_out;
  float* ws = (float*)d_ws;

  const bool useKT = (ws_size >= 163840ull * sizeof(float));
  float* kt1 = ws;
  float* kt2 = ws + 65536;
  float* kddt = ws + 131072;

  dim3 grid(SDIM / SBLK, TDIM / TT);  // (8, 256) = 2048 blocks
  if (useKT) {
    hipLaunchKernelGGL(chp_prep, dim3(640), dim3(256), 0, stream, kw1, kw2, kdd, kt1,
                       kt2, kddt);
    hipLaunchKernelGGL((chp_main<true>), grid, dim3(THREADS), 0, stream, in, w, qw1,
                       qw2, qdd, kw1, kw2, kdd, kt1, kt2, kddt, out);
  } else {
    hipLaunchKernelGGL((chp_main<false>), grid, dim3(THREADS), 0, stream, in, w, qw1,
                       qw2, qdd, kw1, kw2, kdd, nullptr, nullptr, nullptr, out);
  }
}